// Round 11
// baseline (40.678 us; speedup 1.0000x reference)
//
#include <hip/hip_runtime.h>

#define BS 16
#define S  256
#define H  1024
#define T  32

// ws layout (floats): ps[512] | p1[4096*32] | p2[4096*32]   (p1,p2 FINAL)
#define PS_OFF 0
#define P1_OFF 512
#define P2_OFF (P1_OFF + BS * S * T)

typedef __bf16 bf16x8 __attribute__((ext_vector_type(8)));
typedef float  f32x4  __attribute__((ext_vector_type(4)));
typedef float  f4n    __attribute__((ext_vector_type(4)));   // native for nt-store

__device__ inline bf16x8 to_bf8(float4 lo, float4 hi) {
    bf16x8 r;
    r[0] = (__bf16)lo.x; r[1] = (__bf16)lo.y; r[2] = (__bf16)lo.z; r[3] = (__bf16)lo.w;
    r[4] = (__bf16)hi.x; r[5] = (__bf16)hi.y; r[6] = (__bf16)hi.z; r[7] = (__bf16)hi.w;
    return r;
}

// ---------------------------------------------------------------------------
// Kernel A: 1024-thread blocks (16 waves).
//   blk < 32 : ps — one wave per (b,t): o = blk*16+wv, coalesced + shfl_xor.
//   blk >= 32: GEMM, BM=16, K-split INTRA-block: wave wv -> k-chunk ks=wv>>2,
//     col-group cg=wv&3. Per wave: R5-proven volume (16 cols x 256 k B-frags
//     in VGPRs, 8 MFMAs, 1 A-frag ds_read each). E staged ONCE as bf16
//     (33 KB, stride 1032 -> 2-way bank alias = free). Cross-wave k-reduce
//     via 16 KB pacc + 1 barrier; p1/p2 written FINAL (no reduce kernel).
// ---------------------------------------------------------------------------
__global__ __launch_bounds__(1024) void gemm_ps(
    const float* __restrict__ seq, const float* __restrict__ E,
    const float* __restrict__ W, const float* __restrict__ bias,
    float* __restrict__ ws)
{
    const int tid = threadIdx.x;
    const int lane = tid & 63, wv = tid >> 6;

    if (blockIdx.x < 32) {
        // ---- ps[b,t] = seq[b,:] . W[t,2H:3H] + bias[t], wave-parallel ----
        float* ps = ws + PS_OFF;
        const int o = blockIdx.x * 16 + wv;           // 0..511
        const int bb = o >> 5, t = o & 31;
        const float4* sp = (const float4*)(seq + (size_t)bb * H) + lane * 4;
        const float4* wp = (const float4*)(W + (size_t)t * (3 * H) + 2 * H) + lane * 4;
        float acc = 0.f;
        #pragma unroll
        for (int k = 0; k < 4; ++k) {
            float4 a = sp[k], w = wp[k];
            acc += a.x * w.x + a.y * w.y + a.z * w.z + a.w * w.w;
        }
        #pragma unroll
        for (int m = 32; m >= 1; m >>= 1) acc += __shfl_xor(acc, m);
        if (lane == 0) ps[o] = acc + bias[t];
        return;
    }

    __shared__ __align__(16) __bf16 Ebf[16][1032];    // 33 KB
    __shared__ __align__(16) float  pacc[4][16][64];  // 16 KB

    const int m0 = (blockIdx.x - 32) * 16;
    const int ks = wv >> 2;                           // k-chunk 0..3
    const int cg = wv & 3;                            // col-group 0..3
    const int kbeg = ks * 256;

    // ---- wave-private B fragments: 16 cols x 256 k (R5-proven volume) ----
    const int col = cg * 16 + (lane & 15);            // output col 0..63
    const int ksub = (lane >> 4) * 8;                 // k sub-offset 0/8/16/24
    const float* wbase = W + (size_t)(col & 31) * (3 * H)
                           + ((col >= 32) ? H : 0) + kbeg + ksub;
    bf16x8 bfrag[8];
    #pragma unroll
    for (int s = 0; s < 8; ++s)
        bfrag[s] = to_bf8(*(const float4*)(wbase + s * 32),
                          *(const float4*)(wbase + s * 32 + 4));

    // ---- stage E tile 16x1024 -> bf16 LDS (coalesced 32B/lane reads) ----
    #pragma unroll
    for (int i = 0; i < 2; ++i) {
        int c = tid + i * 1024;                       // 0..2047 chunks of 8
        int row = c >> 7, c8 = c & 127;
        const float4* src = (const float4*)(E + (size_t)(m0 + row) * H + c8 * 8);
        *(bf16x8*)&Ebf[row][c8 * 8] = to_bf8(src[0], src[1]);
    }
    __syncthreads();

    // ---- 8 MFMAs: this wave's 16x16 tile over its k-chunk ----
    f32x4 acc = {0.f, 0.f, 0.f, 0.f};
    const int erow = lane & 15;
    const int kof = kbeg + ksub;
    #pragma unroll
    for (int s = 0; s < 8; ++s) {
        bf16x8 a = *(const bf16x8*)&Ebf[erow][kof + s * 32];
        acc = __builtin_amdgcn_mfma_f32_16x16x32_bf16(a, bfrag[s], acc, 0, 0, 0);
    }

    // ---- partial tiles -> LDS (D layout: col=lane&15, row=(lane>>4)*4+r) ----
    const int orow = (lane >> 4) * 4;
    #pragma unroll
    for (int r = 0; r < 4; ++r)
        pacc[ks][orow + r][col] = acc[r];
    __syncthreads();

    // ---- k-reduce + final write: thread t -> (row=t>>6, col=t&63) ----
    {
        const int row = tid >> 6, c = tid & 63;
        float v = (pacc[0][row][c] + pacc[1][row][c])
                + (pacc[2][row][c] + pacc[3][row][c]);
        if (c < 32) (ws + P1_OFF)[(size_t)(m0 + row) * T + c] = v;
        else        (ws + P2_OFF)[(size_t)(m0 + row) * T + (c - 32)] = v;
    }
}

// ---------------------------------------------------------------------------
// Kernel B: out[b,i,j,t] = (p1[b,i,t] + ps[b,t]) + p2[b,j,t]
//   Barrier-free prologue; NON-TEMPORAL stores (write-once output, keeps
//   p2 hot in L2 instead of being evicted by 134 MB of write-allocate).
// ---------------------------------------------------------------------------
__global__ __launch_bounds__(256) void bcast_add(
    const float* __restrict__ ws, float* __restrict__ out)
{
    const int blk = blockIdx.x;
    const int b = blk >> 8, i = blk & 255;
    const int tid = threadIdx.x;

    const float4 s1v = *(const float4*)((ws + P1_OFF)
                       + (size_t)(b * S + i) * T + (tid & 7) * 4);
    const float4 psv = *(const float4*)((ws + PS_OFF) + b * T + (tid & 7) * 4);
    float4 s;
    s.x = s1v.x + psv.x; s.y = s1v.y + psv.y;
    s.z = s1v.z + psv.z; s.w = s1v.w + psv.w;

    const float4* p2v = (const float4*)(ws + P2_OFF) + (size_t)b * (S * T / 4);
    float4* ov = (float4*)out + (size_t)(b * S + i) * (S * T / 4);

    #pragma unroll
    for (int k = tid; k < S * T / 4; k += 256) {
        float4 v = p2v[k];
        f4n r;
        r.x = v.x + s.x; r.y = v.y + s.y; r.z = v.z + s.z; r.w = v.w + s.w;
        __builtin_nontemporal_store(r, (f4n*)&ov[k]);
    }
}

extern "C" void kernel_launch(void* const* d_in, const int* in_sizes, int n_in,
                              void* d_out, int out_size, void* d_ws, size_t ws_size,
                              hipStream_t stream)
{
    const float* seq  = (const float*)d_in[0];   // (16,1024)
    const float* E    = (const float*)d_in[1];   // (16,256,1024)
    const float* W    = (const float*)d_in[2];   // (32,3072)
    const float* bias = (const float*)d_in[3];   // (32,)
    float* out = (float*)d_out;                  // (16,256,256,32) f32
    float* ws  = (float*)d_ws;                   // ~1.05 MB used

    gemm_ps<<<288, 1024, 0, stream>>>(seq, E, W, bias, ws);
    bcast_add<<<BS * S, 256, 0, stream>>>(ws, out);
}

// Round 12
// 38.582 us; speedup vs baseline: 1.0543x; 1.0543x over previous
//
#include <hip/hip_runtime.h>

#define BS 16
#define S  256
#define H  1024
#define T  32
#define KSPLIT 8
#define KCH (H / KSPLIT)    // 128 k per gemm block
#define BM 32               // rows per gemm block

// ws layout (floats): pp[8][4096][64] | ps[512] | p1[4096*32] | p2[4096*32]
#define PP_OFF 0
#define PP_SZ  (KSPLIT * BS * S * 64)           // 2097152 floats (8.4 MB)
#define PS_OFF (PP_OFF + PP_SZ)
#define P1_OFF (PS_OFF + 512)
#define P2_OFF (P1_OFF + BS * S * T)

typedef __bf16 bf16x8 __attribute__((ext_vector_type(8)));
typedef float  f32x4  __attribute__((ext_vector_type(4)));

__device__ inline bf16x8 to_bf8(float4 lo, float4 hi) {
    bf16x8 r;
    r[0] = (__bf16)lo.x; r[1] = (__bf16)lo.y; r[2] = (__bf16)lo.z; r[3] = (__bf16)lo.w;
    r[4] = (__bf16)hi.x; r[5] = (__bf16)hi.y; r[6] = (__bf16)hi.z; r[7] = (__bf16)hi.w;
    return r;
}

// ---------------------------------------------------------------------------
// Kernel A (R10 structure, KSPLIT=8):
//   blk < 128 : ps — one wave per (b,t), coalesced + shfl_xor reduce.
//   blk >= 128: GEMM partials. g=blk-128: ks=g>>7 (k-chunk of 128),
//     m-tile=32 rows (m0=(g&127)*32); wave w owns cols [16w,16w+16).
//     Per wave: 4 B-frag loads, 8 MFMAs. E staged as bf16 (8.5 KB LDS).
//     1152 blocks -> ~4.5 blocks/CU: latency actually hidden.
// ---------------------------------------------------------------------------
__global__ __launch_bounds__(256) void gemm_ps(
    const float* __restrict__ seq, const float* __restrict__ E,
    const float* __restrict__ W, const float* __restrict__ bias,
    float* __restrict__ ws)
{
    const int tid = threadIdx.x;
    const int lane = tid & 63, wv = tid >> 6;

    if (blockIdx.x < 128) {
        // ---- ps[b,t] = seq[b,:] . W[t,2H:3H] + bias[t], wave-parallel ----
        float* ps = ws + PS_OFF;
        const int o = blockIdx.x * 4 + wv;            // 0..511
        const int bb = o >> 5, t = o & 31;
        const float4* sp = (const float4*)(seq + (size_t)bb * H) + lane * 4;
        const float4* wp = (const float4*)(W + (size_t)t * (3 * H) + 2 * H) + lane * 4;
        float acc = 0.f;
        #pragma unroll
        for (int k = 0; k < 4; ++k) {
            float4 a = sp[k], w = wp[k];
            acc += a.x * w.x + a.y * w.y + a.z * w.z + a.w * w.w;
        }
        #pragma unroll
        for (int m = 32; m >= 1; m >>= 1) acc += __shfl_xor(acc, m);
        if (lane == 0) ps[o] = acc + bias[t];
        return;
    }

    __shared__ __align__(16) __bf16 Ebf[BM][136];     // 8.5 KB

    const int g = blockIdx.x - 128;
    const int ks = g >> 7;                            // k-chunk 0..7
    const int m0 = (g & 127) * BM;
    const int kbeg = ks * KCH;

    // ---- wave-private B fragments: 16 cols x 128 k ----
    const int nb = wv * 16;
    const int wrow = nb + (lane & 15);                // output col 0..63
    const int ksub = (lane >> 4) * 8;                 // k sub-offset 0/8/16/24
    const float* wbase = W + (size_t)(wrow & 31) * (3 * H)
                           + ((wrow >> 5) ? H : 0) + kbeg + ksub;
    bf16x8 bfrag[4];
    #pragma unroll
    for (int s = 0; s < 4; ++s)
        bfrag[s] = to_bf8(*(const float4*)(wbase + s * 32),
                          *(const float4*)(wbase + s * 32 + 4));

    // ---- stage E tile 32x128 -> bf16 LDS (coalesced 32B/lane reads) ----
    #pragma unroll
    for (int i = 0; i < 2; ++i) {
        int f = tid + i * 256;                        // 0..511
        int row = f >> 4, c8 = f & 15;                // 32 rows x 16 chunks
        const float4* src = (const float4*)(E + (size_t)(m0 + row) * H
                                            + kbeg + c8 * 8);
        *(bf16x8*)&Ebf[row][c8 * 8] = to_bf8(src[0], src[1]);
    }
    __syncthreads();                                  // the only barrier

    // ---- 8 MFMAs: 2 m-subtiles x 4 k-steps ----
    f32x4 acc0 = {0.f,0.f,0.f,0.f}, acc1 = {0.f,0.f,0.f,0.f};
    const int erow = lane & 15;
    #pragma unroll
    for (int s = 0; s < 4; ++s) {
        bf16x8 a0 = *(const bf16x8*)&Ebf[erow][s * 32 + ksub];
        bf16x8 a1 = *(const bf16x8*)&Ebf[erow + 16][s * 32 + ksub];
        acc0 = __builtin_amdgcn_mfma_f32_16x16x32_bf16(a0, bfrag[s], acc0, 0, 0, 0);
        acc1 = __builtin_amdgcn_mfma_f32_16x16x32_bf16(a1, bfrag[s], acc1, 0, 0, 0);
    }

    // ---- store partials: D layout col=lane&15, row=(lane>>4)*4+r ----
    float* pp = ws + PP_OFF + (size_t)ks * (BS * S * 64);
    const int orow = (lane >> 4) * 4;
    const int ocol = nb + (lane & 15);
    #pragma unroll
    for (int r = 0; r < 4; ++r) {
        pp[(size_t)(m0 + orow + r) * 64 + ocol]      = acc0[r];
        pp[(size_t)(m0 + 16 + orow + r) * 64 + ocol] = acc1[r];
    }
}

// ---------------------------------------------------------------------------
// Kernel B: reduce KSPLIT partials; split cols into p1 (ps folded) and p2.
// ---------------------------------------------------------------------------
__global__ __launch_bounds__(256) void reduce_p(float* __restrict__ ws)
{
    const int o = blockIdx.x * 256 + threadIdx.x;     // float4 idx, 0..65535
    const float4* pp = (const float4*)(ws + PP_OFF);
    float4 v = pp[o];
    #pragma unroll
    for (int ks = 1; ks < KSPLIT; ++ks) {
        float4 u = pp[o + ks * (PP_SZ / KSPLIT / 4)];
        v.x += u.x; v.y += u.y; v.z += u.z; v.w += u.w;
    }
    const int row = o >> 4, c4 = o & 15;              // row 0..4095
    if (c4 < 8) {
        const int b = row >> 8;
        float4 s = ((const float4*)(ws + PS_OFF))[b * 8 + c4];
        v.x += s.x; v.y += s.y; v.z += s.z; v.w += s.w;
        ((float4*)(ws + P1_OFF))[row * 8 + c4] = v;
    } else {
        ((float4*)(ws + P2_OFF))[row * 8 + (c4 - 8)] = v;
    }
}

// ---------------------------------------------------------------------------
// Kernel C (R10-proven): out[b,i,j,t] = p1[b,i,t] + p2[b,j,t]
//   Barrier-free prologue: s read directly (8x16B segments/wave, L2-hot).
// ---------------------------------------------------------------------------
__global__ __launch_bounds__(256) void bcast_add(
    const float* __restrict__ ws, float* __restrict__ out)
{
    const int blk = blockIdx.x;
    const int b = blk >> 8, i = blk & 255;
    const int tid = threadIdx.x;

    const float4 s = *(const float4*)((ws + P1_OFF)
                     + (size_t)(b * S + i) * T + (tid & 7) * 4);
    const float4* p2v = (const float4*)(ws + P2_OFF) + (size_t)b * (S * T / 4);
    float4* ov = (float4*)out + (size_t)(b * S + i) * (S * T / 4);

    #pragma unroll
    for (int k = tid; k < S * T / 4; k += 256) {
        float4 v = p2v[k];
        float4 r;
        r.x = v.x + s.x; r.y = v.y + s.y; r.z = v.z + s.z; r.w = v.w + s.w;
        ov[k] = r;
    }
}

extern "C" void kernel_launch(void* const* d_in, const int* in_sizes, int n_in,
                              void* d_out, int out_size, void* d_ws, size_t ws_size,
                              hipStream_t stream)
{
    const float* seq  = (const float*)d_in[0];   // (16,1024)
    const float* E    = (const float*)d_in[1];   // (16,256,1024)
    const float* W    = (const float*)d_in[2];   // (32,3072)
    const float* bias = (const float*)d_in[3];   // (32,)
    float* out = (float*)d_out;                  // (16,256,256,32) f32
    float* ws  = (float*)d_ws;                   // ~9.5 MB used

    gemm_ps<<<128 + KSPLIT * 128, 256, 0, stream>>>(seq, E, W, bias, ws);
    reduce_p<<<256, 256, 0, stream>>>(ws);
    bcast_add<<<BS * S, 256, 0, stream>>>(ws, out);
}